// Round 1
// baseline (774.803 us; speedup 1.0000x reference)
//
#include <hip/hip_runtime.h>

#define NN   8192
#define FEAT 192
#define HID  256
#define NCLS 1000
#define KNN  9
#define NPP  512          // nodes per image (8192 / 16)
#define NIMG 16
#define FINF 3.402823466e38f

// ---------------------------------------------------------------------------
// sorted-ascending top-9 insertion, all indices constant after unroll (stays
// in VGPRs). Strict '<' keeps earlier (lower col) on ties, matching lax.top_k.
__device__ __forceinline__ void topk_insert(float (&tv)[KNN], int (&tc)[KNN],
                                            float v, int c) {
  if (v < tv[KNN - 1]) {
    tv[KNN - 1] = v; tc[KNN - 1] = c;
#pragma unroll
    for (int p = KNN - 1; p > 0; --p) {
      if (tv[p] < tv[p - 1]) {
        float fv = tv[p]; tv[p] = tv[p - 1]; tv[p - 1] = fv;
        int   fi = tc[p]; tc[p] = tc[p - 1]; tc[p - 1] = fi;
      }
    }
  }
}

// ---------------------------------------------------------------------------
__global__ __launch_bounds__(256) void k_norms(const float* __restrict__ x,
                                               float* __restrict__ sq) {
  int wid  = (blockIdx.x * 256 + threadIdx.x) >> 6;
  int lane = threadIdx.x & 63;
  if (wid >= NN) return;
  const float* row = x + (size_t)wid * FEAT;
  float s = 0.f;
  for (int f = lane; f < FEAT; f += 64) { float v = row[f]; s += v * v; }
#pragma unroll
  for (int off = 32; off > 0; off >>= 1) s += __shfl_down(s, off);
  if (lane == 0) sq[wid] = s;
}

// ---------------------------------------------------------------------------
// 128x128 tile of the distance matrix, K=192, fp32. Epilogue: per-row top-9
// within this column block -> candidate arrays [row][colblock][9].
// Rank by v = sq[j] - 2*dot (sq[i] is a per-row constant, ranking-invariant).
__global__ __launch_bounds__(256) void k_dist_topk(
    const float* __restrict__ x, const float* __restrict__ sq,
    float* __restrict__ cand_v, int* __restrict__ cand_i) {
  __shared__ float As[8][128];
  __shared__ float Bs[8][128];
  __shared__ float Ds[128][129];   // +1 pad: scan reads conflict-free

  const int t  = threadIdx.x;
  const int tx = t & 15, ty = t >> 4;
  const int rowStart = blockIdx.y * 128;
  const int colStart = blockIdx.x * 128;
  const int lr = t >> 1, lk = (t & 1) * 4;

  float acc[8][8] = {};

  for (int k0 = 0; k0 < FEAT; k0 += 8) {
    float4 av = *(const float4*)(x + (size_t)(rowStart + lr) * FEAT + k0 + lk);
    float4 bv = *(const float4*)(x + (size_t)(colStart + lr) * FEAT + k0 + lk);
    __syncthreads();
    As[lk + 0][lr] = av.x; As[lk + 1][lr] = av.y;
    As[lk + 2][lr] = av.z; As[lk + 3][lr] = av.w;
    Bs[lk + 0][lr] = bv.x; Bs[lk + 1][lr] = bv.y;
    Bs[lk + 2][lr] = bv.z; Bs[lk + 3][lr] = bv.w;
    __syncthreads();
#pragma unroll
    for (int k = 0; k < 8; ++k) {
      float a[8], b[8];
      *(float4*)&a[0] = *(const float4*)&As[k][ty * 8];
      *(float4*)&a[4] = *(const float4*)&As[k][ty * 8 + 4];
      *(float4*)&b[0] = *(const float4*)&Bs[k][tx * 8];
      *(float4*)&b[4] = *(const float4*)&Bs[k][tx * 8 + 4];
#pragma unroll
      for (int i = 0; i < 8; ++i)
#pragma unroll
        for (int j = 0; j < 8; ++j)
          acc[i][j] = fmaf(a[i], b[j], acc[i][j]);
    }
  }

  float sqc[8];
#pragma unroll
  for (int j = 0; j < 8; ++j) sqc[j] = sq[colStart + tx * 8 + j];
#pragma unroll
  for (int i = 0; i < 8; ++i)
#pragma unroll
    for (int j = 0; j < 8; ++j)
      Ds[ty * 8 + i][tx * 8 + j] = sqc[j] - 2.0f * acc[i][j];
  __syncthreads();

  // two threads per row scan 64 cols each
  const int row = t >> 1, half = t & 1;
  float tv[KNN]; int tc[KNN];
#pragma unroll
  for (int n = 0; n < KNN; ++n) { tv[n] = FINF; tc[n] = -1; }
  for (int c = 0; c < 64; ++c) {
    int col = half * 64 + c;
    topk_insert(tv, tc, Ds[row][col], colStart + col);
  }
  __syncthreads();          // scan done before reusing Ds as merge scratch
  if (half) {
#pragma unroll
    for (int n = 0; n < KNN; ++n) {
      Ds[row][n]      = tv[n];
      Ds[row][16 + n] = __int_as_float(tc[n]);
    }
  }
  __syncthreads();
  if (!half) {
#pragma unroll
    for (int n = 0; n < KNN; ++n)
      topk_insert(tv, tc, Ds[row][n], __float_as_int(Ds[row][16 + n]));
    int base = ((rowStart + row) * 64 + blockIdx.x) * KNN;
#pragma unroll
    for (int n = 0; n < KNN; ++n) { cand_v[base + n] = tv[n]; cand_i[base + n] = tc[n]; }
  }
}

// ---------------------------------------------------------------------------
// one wave per row: merge 64 colblocks x 9 = 576 candidates -> final 9 idx
__global__ __launch_bounds__(256) void k_reduce_topk(
    const float* __restrict__ cand_v, const int* __restrict__ cand_i,
    int* __restrict__ idx) {
  int wid  = (blockIdx.x * 256 + threadIdx.x) >> 6;
  int lane = threadIdx.x & 63;
  if (wid >= NN) return;
  const float* cv = cand_v + (size_t)wid * 576;
  const int*   ci = cand_i + (size_t)wid * 576;
  float tv[KNN]; int tc[KNN];
#pragma unroll
  for (int n = 0; n < KNN; ++n) { tv[n] = FINF; tc[n] = -1; }
#pragma unroll
  for (int m = 0; m < KNN; ++m)
    topk_insert(tv, tc, cv[lane + 64 * m], ci[lane + 64 * m]);

  for (int r = 0; r < KNN; ++r) {
    float bv = tv[0]; int bc = tc[0];
#pragma unroll
    for (int n = 1; n < KNN; ++n)
      if (tv[n] < bv) { bv = tv[n]; bc = tc[n]; }
#pragma unroll
    for (int off = 32; off > 0; off >>= 1) {
      float ov = __shfl_xor(bv, off);
      int   oc = __shfl_xor(bc, off);
      if (ov < bv || (ov == bv && oc < bc)) { bv = ov; bc = oc; }
    }
    // consume winner (cols are globally unique per row)
#pragma unroll
    for (int n = 0; n < KNN; ++n)
      if (tc[n] == bc) tv[n] = FINF;
    if (lane == 0) idx[wid * KNN + r] = bc;
  }
}

// ---------------------------------------------------------------------------
// one wave per row: agg[i] = mean_{j<9} h[idx[i][j]]  (all lanes share the
// neighbor list -> each read is 64 consecutive floats, coalesced)
__global__ __launch_bounds__(256) void k_gather(
    const float* __restrict__ h, const int* __restrict__ idx,
    float* __restrict__ agg, int C) {
  int wid  = (blockIdx.x * 256 + threadIdx.x) >> 6;
  int lane = threadIdx.x & 63;
  if (wid >= NN) return;
  int nb[KNN];
#pragma unroll
  for (int n = 0; n < KNN; ++n) nb[n] = idx[wid * KNN + n];
  for (int f = lane; f < C; f += 64) {
    float s = 0.f;
#pragma unroll
    for (int n = 0; n < KNN; ++n) s += h[(size_t)nb[n] * C + f];
    agg[(size_t)wid * C + f] = s * (1.0f / KNN);
  }
}

// ---------------------------------------------------------------------------
__global__ void k_zero(float* __restrict__ out, int n) {
  int i = blockIdx.x * 256 + threadIdx.x;
  if (i < n) out[i] = 0.f;
}

// ---------------------------------------------------------------------------
// h = relu([A1|A2] @ [W1;W2] + bias); POOL: fused global mean pool (atomic)
template <int BM, int BN, int TM, int TN, bool POOL>
__global__ __launch_bounds__(256) void k_sage_gemm(
    const float* __restrict__ A1, const float* __restrict__ A2, int K1, int K2,
    const float* __restrict__ W1, const float* __restrict__ W2,
    const float* __restrict__ bias, float* __restrict__ out, int N) {
  constexpr int BK = 8;
  __shared__ float As[BK][BM];
  __shared__ float Bs[BK][BN];
  __shared__ float red[POOL ? (BM / TM) * BN : 1];

  const int t  = threadIdx.x;
  const int tx = t & 15, ty = t >> 4;
  const int rowStart = blockIdx.y * BM;
  const int colStart = blockIdx.x * BN;

  const int  alr = t >> 1, alk = (t & 1) * 4;
  const bool aact = t < BM * 2;
  constexpr int BW = BN / 4;
  const int  bkr = t / BW, bnc = (t % BW) * 4;
  const bool bact = t < BK * BW;

  float acc[TM][TN] = {};
  const int KT = K1 + K2;

  for (int k0 = 0; k0 < KT; k0 += BK) {
    float4 av = {0, 0, 0, 0}, bv = {0, 0, 0, 0};
    if (aact) {
      int kk = k0 + alk;
      const float* src = (kk < K1)
          ? A1 + (size_t)(rowStart + alr) * K1 + kk
          : A2 + (size_t)(rowStart + alr) * K2 + (kk - K1);
      av = *(const float4*)src;
    }
    if (bact) {
      int kk = k0 + bkr;
      const float* wsrc = (kk < K1) ? W1 + (size_t)kk * N
                                    : W2 + (size_t)(kk - K1) * N;
      int col = colStart + bnc;
      if (col < N) bv = *(const float4*)(wsrc + col);
    }
    __syncthreads();
    if (aact) {
      As[alk + 0][alr] = av.x; As[alk + 1][alr] = av.y;
      As[alk + 2][alr] = av.z; As[alk + 3][alr] = av.w;
    }
    if (bact) *(float4*)&Bs[bkr][bnc] = bv;
    __syncthreads();
#pragma unroll
    for (int k = 0; k < BK; ++k) {
      float a[TM], b[TN];
#pragma unroll
      for (int i = 0; i < TM; i += 4)
        *(float4*)&a[i] = *(const float4*)&As[k][ty * TM + i];
#pragma unroll
      for (int j = 0; j < TN; j += 4)
        *(float4*)&b[j] = *(const float4*)&Bs[k][tx * TN + j];
#pragma unroll
      for (int i = 0; i < TM; ++i)
#pragma unroll
        for (int j = 0; j < TN; ++j)
          acc[i][j] = fmaf(a[i], b[j], acc[i][j]);
    }
  }

  float bvals[TN];
#pragma unroll
  for (int j = 0; j < TN; ++j) {
    int col = colStart + tx * TN + j;
    bvals[j] = (col < N) ? bias[col] : 0.f;
  }

  if (!POOL) {
#pragma unroll
    for (int i = 0; i < TM; ++i) {
      int row = rowStart + ty * TM + i;
#pragma unroll
      for (int j = 0; j < TN; ++j) {
        int col = colStart + tx * TN + j;
        if (col < N)
          out[(size_t)row * N + col] = fmaxf(acc[i][j] + bvals[j], 0.f);
      }
    }
  } else {
    float srow[TN];
#pragma unroll
    for (int j = 0; j < TN; ++j) {
      float s = 0.f;
#pragma unroll
      for (int i = 0; i < TM; ++i) s += fmaxf(acc[i][j] + bvals[j], 0.f);
      srow[j] = s;
    }
#pragma unroll
    for (int j = 0; j < TN; ++j) red[ty * BN + tx * TN + j] = srow[j];
    __syncthreads();
    if (t < BN) {
      int col = colStart + t;
      if (col < N) {
        float s = 0.f;
#pragma unroll
        for (int r = 0; r < BM / TM; ++r) s += red[r * BN + t];
        int img = rowStart / NPP;   // BM=128 divides NPP=512: no straddle
        atomicAdd(out + (size_t)img * NCLS + col, s * (1.0f / NPP));
      }
    }
  }
}

// ---------------------------------------------------------------------------
extern "C" void kernel_launch(void* const* d_in, const int* in_sizes, int n_in,
                              void* d_out, int out_size, void* d_ws,
                              size_t ws_size, hipStream_t stream) {
  const float* x    = (const float*)d_in[0];
  const float* w_l0 = (const float*)d_in[1];
  const float* b_l0 = (const float*)d_in[2];
  const float* w_r0 = (const float*)d_in[3];
  const float* w_l1 = (const float*)d_in[4];
  const float* b_l1 = (const float*)d_in[5];
  const float* w_r1 = (const float*)d_in[6];
  const float* w_l2 = (const float*)d_in[7];
  const float* b_l2 = (const float*)d_in[8];
  const float* w_r2 = (const float*)d_in[9];
  float* out = (float*)d_out;

  char* ws = (char*)d_ws;
  // layout (bytes): sq[32768] | idx[294912] | cand region [37.75 MB]
  // cand region is dead after k_reduce_topk and reused for agg/h0/h1.
  float* sq     = (float*)(ws);
  int*   idx    = (int*)(ws + 32768);
  float* cand_v = (float*)(ws + 327680);
  int*   cand_i = (int*)(ws + 327680 + 18874368);
  float* agg    = (float*)(ws + 327680);                 // 8192*256*4
  float* h0     = (float*)(ws + 327680 + 8388608);
  float* h1     = (float*)(ws + 327680 + 16777216);

  // 1) row norms
  k_norms<<<2048, 256, 0, stream>>>(x, sq);
  // 2) distances + per-colblock top-9 candidates
  k_dist_topk<<<dim3(64, 64), 256, 0, stream>>>(x, sq, cand_v, cand_i);
  // 3) merge candidates -> idx[8192][9]
  k_reduce_topk<<<2048, 256, 0, stream>>>(cand_v, cand_i, idx);
  // 4) zero pooled output (re-poisoned to 0xAA before every timed launch)
  k_zero<<<(NIMG * NCLS + 255) / 256, 256, 0, stream>>>(out, NIMG * NCLS);
  // 5) layer 0
  k_gather<<<2048, 256, 0, stream>>>(x, idx, agg, FEAT);
  k_sage_gemm<64, 64, 4, 4, false><<<dim3(HID / 64, NN / 64), 256, 0, stream>>>(
      agg, x, FEAT, FEAT, w_l0, w_r0, b_l0, h0, HID);
  // 6) layer 1
  k_gather<<<2048, 256, 0, stream>>>(h0, idx, agg, HID);
  k_sage_gemm<64, 64, 4, 4, false><<<dim3(HID / 64, NN / 64), 256, 0, stream>>>(
      agg, h0, HID, HID, w_l1, w_r1, b_l1, h1, HID);
  // 7) layer 2 + fused global mean pool
  k_gather<<<2048, 256, 0, stream>>>(h1, idx, agg, HID);
  k_sage_gemm<128, 128, 8, 8, true><<<dim3(8, NN / 128), 256, 0, stream>>>(
      agg, h1, HID, HID, w_l2, w_r2, b_l2, out, NCLS);
}